// Round 10
// baseline (469.389 us; speedup 1.0000x reference)
//
#include <hip/hip_runtime.h>
#include <cstddef>

// Problem constants: B=4, S=2048, D=1024, H=16, HD=64
constexpr int Bn  = 4;
constexpr int Sn  = 2048;
constexpr int Dn  = 1024;
constexpr int Hn  = 16;
constexpr int HDn = 64;

typedef __bf16 bf16;
typedef __attribute__((ext_vector_type(8))) __bf16 bf16x8;
typedef __attribute__((ext_vector_type(4))) __bf16 bf16x4;
typedef __attribute__((ext_vector_type(4))) float  f32x4;

typedef __attribute__((address_space(1))) const void gvoid;
typedef __attribute__((address_space(3))) void lvoid;

// ---------------------------------------------------------------------------
// Elementwise fp32 -> bf16 (x staging)
// ---------------------------------------------------------------------------
__global__ __launch_bounds__(256) void conv_f32_bf16_k(
    const float* __restrict__ in, bf16* __restrict__ out, int n)
{
    int i = (blockIdx.x * 256 + threadIdx.x) * 4;
    if (i + 3 < n) {
        float4 v = *(const float4*)(in + i);
        bf16 o[4] = {(bf16)v.x, (bf16)v.y, (bf16)v.z, (bf16)v.w};
        *(ulong1*)(out + i) = *(ulong1*)o;  // 8B store
    }
}

// ---------------------------------------------------------------------------
// Bias concat: [bq|bk|bv] -> float[3072]
// ---------------------------------------------------------------------------
__global__ __launch_bounds__(256) void bias_cat_k(
    const float* __restrict__ bq, const float* __restrict__ bk,
    const float* __restrict__ bv, float* __restrict__ o)
{
    const int i = blockIdx.x * 256 + threadIdx.x;   // grid 12 -> 3072
    if (i < 1024)      o[i] = bq[i];
    else if (i < 2048) o[i] = bk[i - 1024];
    else if (i < 3072) o[i] = bv[i - 2048];
}

// ---------------------------------------------------------------------------
// Weight transpose + convert: W[k][n] fp32 -> Wt[n][k] bf16. 64x64 tiles.
// ---------------------------------------------------------------------------
__global__ __launch_bounds__(256) void conv_wt_k(
    const float* __restrict__ w0, const float* __restrict__ w1,
    const float* __restrict__ w2, const float* __restrict__ w3,
    bf16* __restrict__ o0, bf16* __restrict__ o1,
    bf16* __restrict__ o2, bf16* __restrict__ o3)
{
    const float* W = (blockIdx.z == 0) ? w0 : (blockIdx.z == 1) ? w1
                   : (blockIdx.z == 2) ? w2 : w3;
    bf16* O = (blockIdx.z == 0) ? o0 : (blockIdx.z == 1) ? o1
            : (blockIdx.z == 2) ? o2 : o3;
    __shared__ float t[64][65];
    const int tid = threadIdx.x;
    const int k0 = blockIdx.x * 64;   // row of W (k-dim)
    const int n0 = blockIdx.y * 64;   // col of W (n-dim)
    #pragma unroll
    for (int p = 0; p < 16; ++p) {
        const int idx = p * 256 + tid;
        const int r = idx >> 6, c = idx & 63;
        t[r][c] = W[(size_t)(k0 + r) * Dn + n0 + c];
    }
    __syncthreads();
    #pragma unroll
    for (int p = 0; p < 16; ++p) {
        const int idx = p * 256 + tid;
        const int r = idx >> 6, c = idx & 63;   // r: n-offset, c: k-offset
        O[(size_t)(n0 + r) * Dn + k0 + c] = (bf16)t[c][r];
    }
}

// ---------------------------------------------------------------------------
// 256x256-tile MFMA GEMM (R9 post-mortem: GEMMs are STAGING-TRAFFIC bound —
// 786 MB staged at ~6.3 TB/s == the observed ~190 us. 256^2 tiles halve the
// staged bytes/FLOP; XCD m-chunk swizzle makes A-tile re-reads L2-local).
// 512 thr / 8 waves (2x4); wave (wm,wn) owns 128x64 of C. BK=64, single
// buffer, plain 2-barrier loop (R5-passing semantics; counted-vmcnt and
// sched_barrier pins removed per R8/R9 — null/negative outside 8-phase).
// LDS 64 KB staging; epilogue scratch reuses it.
// ---------------------------------------------------------------------------
#define GEMM_STAGE256(Ap, Bp, k0)                                             \
    {                                                                         \
        _Pragma("unroll")                                                     \
        for (int j = 0; j < 4; ++j) {                                         \
            const int rbase = (w * 4 + j) * 8;                                \
            const int r = rbase + srow;                                       \
            __builtin_amdgcn_global_load_lds(                                 \
                (gvoid*)(Ap + (size_t)(m0 + r) * Dn + (k0) + scol),           \
                (lvoid*)&smem[rbase * 64], 16, 0, 0);                         \
            __builtin_amdgcn_global_load_lds(                                 \
                (gvoid*)(Bp + (size_t)(n0 + r) * Dn + (k0) + scol),           \
                (lvoid*)&smem[16384 + rbase * 64], 16, 0, 0);                 \
        }                                                                     \
    }

#define GEMM_COMPUTE256                                                       \
    {                                                                         \
        _Pragma("unroll")                                                     \
        for (int ks = 0; ks < 64; ks += 32) {                                 \
            bf16x8 af[8], bfr[4];                                             \
            _Pragma("unroll")                                                 \
            for (int fm = 0; fm < 8; ++fm)                                    \
                af[fm] = *(const bf16x8*)&smem[                               \
                    (wm * 128 + fm * 16 + l15) * 64 + ks + quad * 8];         \
            _Pragma("unroll")                                                 \
            for (int fn = 0; fn < 4; ++fn)                                    \
                bfr[fn] = *(const bf16x8*)&smem[16384 +                       \
                    (wn * 64 + fn * 16 + l15) * 64 + ks + quad * 8];          \
            _Pragma("unroll")                                                 \
            for (int fm = 0; fm < 8; ++fm)                                    \
                _Pragma("unroll")                                             \
                for (int fn = 0; fn < 4; ++fn)                                \
                    acc[fm][fn] = __builtin_amdgcn_mfma_f32_16x16x32_bf16(    \
                        af[fm], bfr[fn], acc[fm][fn], 0, 0, 0);               \
        }                                                                     \
    }

#define GEMM_KLOOP256(Ap, Bp)                                                 \
    for (int kt = 0; kt < Dn / 64; ++kt) {                                    \
        GEMM_STAGE256(Ap, Bp, kt * 64);                                       \
        __syncthreads();                                                      \
        GEMM_COMPUTE256;                                                      \
        __syncthreads();                                                      \
    }

// ---------------------------------------------------------------------------
// Final-projection GEMM: out_f32 = A(8192x1024) @ Bt^T + bias. 128 blocks.
// XCD swizzle: 4 consecutive m-tiles per XCD -> A-slice (2MB) L2-resident.
// ---------------------------------------------------------------------------
__global__ __launch_bounds__(512) void gemm_out_k(
    const bf16* __restrict__ A, const bf16* __restrict__ Bt,
    const float* __restrict__ bias, float* __restrict__ outv)
{
    __shared__ __align__(16) bf16 smem[2 * 256 * 64];   // 64 KB

    const int tid  = threadIdx.x;
    const int w    = tid >> 6;            // 0..7
    const int lane = tid & 63;
    const int quad = lane >> 4;
    const int l15  = lane & 15;
    // XCD swizzle: nwg=128, cpx=16; wgid = (bid%8)*16 + bid/8 (bijective)
    const int wgid = (blockIdx.x & 7) * 16 + (blockIdx.x >> 3);
    const int m0   = (wgid >> 2) * 256;   // m-tile major within XCD chunk
    const int n0   = (wgid & 3) * 256;
    const int wm   = w >> 2;              // 0..1
    const int wn   = w & 3;               // 0..3
    const int srow = lane >> 3;
    const int scol = (lane & 7) * 8;

    f32x4 acc[8][4] = {};

    GEMM_KLOOP256(A, Bt);

    #pragma unroll
    for (int fn = 0; fn < 4; ++fn) {
        const int c = n0 + wn * 64 + fn * 16 + l15;
        const float bv = bias[c];
        #pragma unroll
        for (int fm = 0; fm < 8; ++fm)
            #pragma unroll
            for (int i = 0; i < 4; ++i) {
                const int m = m0 + wm * 128 + fm * 16 + quad * 4 + i;
                outv[(size_t)m * Dn + c] = acc[fm][fn][i] + bv;
            }
    }
}

// ---------------------------------------------------------------------------
// FUSED QKV GEMM: A(8192x1024) @ Wqkv^T(3072x1024) + bias_cat. 384 blocks.
// Each 256-wide n-tile lies fully inside one section (256 | 1024):
//   sec 0 (Q): bf16 [b,h,s,hd] scaled by scq; sec 1 (K): bf16 [b,h,s,hd];
//   sec 2 (V): bf16 [b,h,hd,s] via 4-round LDS-transposed coalesced store.
// ---------------------------------------------------------------------------
__global__ __launch_bounds__(512) void gemm_qkv_k(
    const bf16* __restrict__ A, const bf16* __restrict__ Wt,
    const float* __restrict__ bias, bf16* __restrict__ qout,
    bf16* __restrict__ kout, bf16* __restrict__ vout, float scq)
{
    __shared__ __align__(16) bf16 smem[2 * 256 * 64];   // 64 KB

    const int tid  = threadIdx.x;
    const int w    = tid >> 6;
    const int lane = tid & 63;
    const int quad = lane >> 4;
    const int l15  = lane & 15;
    // XCD swizzle: nwg=384, cpx=48; wgid = (bid%8)*48 + bid/8 (bijective).
    // m-tile = wgid/12 -> 4 consecutive m-tiles per XCD (A 2MB L2-resident).
    const int wgid = (blockIdx.x & 7) * 48 + (blockIdx.x >> 3);
    const int m0   = (wgid / 12) * 256;
    const int n0   = (wgid % 12) * 256;   // in [0, 3072)
    const int wm   = w >> 2;
    const int wn   = w & 3;
    const int srow = lane >> 3;
    const int scol = (lane & 7) * 8;

    f32x4 acc[8][4] = {};

    GEMM_KLOOP256(A, Wt);

    const int sec = n0 >> 10;            // 0=Q, 1=K, 2=V (block-uniform)
    const int cb  = n0 & 1023;           // column base within the section

    if (sec < 2) {
        bf16* const outp = sec ? kout : qout;
        const float scale = sec ? 1.0f : scq;
        #pragma unroll
        for (int fn = 0; fn < 4; ++fn) {
            const int cc = cb + wn * 64 + fn * 16 + l15;
            const float bv = bias[n0 + wn * 64 + fn * 16 + l15];
            const int h = cc >> 6, hd = cc & 63;
            #pragma unroll
            for (int fm = 0; fm < 8; ++fm)
                #pragma unroll
                for (int i = 0; i < 4; ++i) {
                    const int m = m0 + wm * 128 + fm * 16 + quad * 4 + i;
                    const int b = m >> 11, s = m & (Sn - 1);
                    outp[(((size_t)(b * Hn + h) * Sn) + s) * HDn + hd] =
                        (bf16)((acc[fm][fn][i] + bv) * scale);
                }
        }
    } else {
        // V: 4 rounds of 64 n-rows through LDS scratch T[64][264] (33.8 KB,
        // reuses smem after the K-loop's final barrier), then coalesced
        // 512B-row stores of Vt[b,h,hd,s].
        bf16* const T = smem;
        const int b   = m0 >> 11;
        const int s0  = m0 & (Sn - 1);
        #pragma unroll
        for (int r = 0; r < 4; ++r) {
            if (wn == r) {           // 2 writer waves (wm=0,1); no barrier inside
                #pragma unroll
                for (int fn = 0; fn < 4; ++fn) {
                    const int row = fn * 16 + l15;                 // 0..63
                    const float bv = bias[n0 + r * 64 + row];
                    #pragma unroll
                    for (int fm = 0; fm < 8; ++fm) {
                        const int col = wm * 128 + fm * 16 + quad * 4;
                        bf16x4 pk;
                        #pragma unroll
                        for (int i = 0; i < 4; ++i)
                            pk[i] = (bf16)(acc[fm][fn][i] + bv);
                        *(bf16x4*)&T[row * 264 + col] = pk;
                    }
                }
            }
            __syncthreads();
            #pragma unroll
            for (int p = 0; p < 4; ++p) {
                const int row = p * 16 + (tid >> 5);               // 0..63
                const int col = (tid & 31) * 8;                    // 0..248
                const int rn  = cb + r * 64 + row;
                const int gh = rn >> 6, ghd = rn & 63;
                bf16x8 v = *(const bf16x8*)&T[row * 264 + col];
                *(bf16x8*)(vout +
                    (((size_t)(b * Hn + gh) * HDn) + ghd) * Sn + s0 + col) = v;
            }
            __syncthreads();
        }
    }
}

// ---------------------------------------------------------------------------
// LDS XOR-swizzle (element-index form): 16B chunk column ^= row&7.
// ---------------------------------------------------------------------------
__device__ __forceinline__ int sidx(int r, int c) {
    return r * 64 + (c ^ ((r & 7) << 3));
}

// ---------------------------------------------------------------------------
// Flash attention (FROZEN from R9-passing version): QBLK=128 @ 512 threads,
// swapped QK^T, log2-domain per-lane softmax, DMA-staged double-buffered
// K/Vt (pre-swizzled source), defer-max, FMA'd query-mask, tree reductions.
// ---------------------------------------------------------------------------
__global__ __launch_bounds__(512, 6) void attn_mfma_k(
    const bf16* __restrict__ Qb, const bf16* __restrict__ Kb,
    const bf16* __restrict__ Vtb, const int* __restrict__ kpm,
    const float* __restrict__ mod, bf16* __restrict__ att)
{
    __shared__ __align__(16) bf16 Ks[2][64 * 64];
    __shared__ __align__(16) bf16 Vts[2][64 * 64];
    __shared__ __align__(16) bf16 Ps[128 * 64];

    const int tid  = threadIdx.x;
    const int w    = tid >> 6;             // 0..7
    const int lane = tid & 63;
    const int quad = lane >> 4;
    const int l15  = lane & 15;
    const int blk  = blockIdx.x;
    const int bh   = blk >> 4;             // q-tile innermost: K/V L2-reuse
    const int q0   = (blk & 15) * 128;
    const int b    = bh >> 4;
    const int h    = bh & 15;
    const size_t base = (size_t)bh * Sn * HDn;

    const int qrow = q0 + w * 16 + l15;    // this lane's softmax q-row
    const bf16x8 qf0 = *(const bf16x8*)(Qb + base + (size_t)qrow * HDn + 0  + quad * 8);
    const bf16x8 qf1 = *(const bf16x8*)(Qb + base + (size_t)qrow * HDn + 32 + quad * 8);

    const float qbias = (kpm[(size_t)b * Sn + qrow] != 0) ? -1e30f : 0.0f;
    const float* modrow = mod + ((size_t)b * Sn + qrow) * Sn;

    float m_r = -1e30f;
    float l_r = 0.0f;
    f32x4 O[4] = {};

    const int rl = lane >> 3;                       // 0..7
    const int cg = ((lane & 7) ^ rl) * 8;           // swizzled source elems
    const int gb = w * 8;                           // group base row

    auto stage = [&](int t, int buf) {
        const int k0 = t * 64;
        __builtin_amdgcn_global_load_lds(
            (gvoid*)(Kb + base + (size_t)(k0 + gb + rl) * HDn + cg),
            (lvoid*)&Ks[buf][gb * 64], 16, 0, 0);
        __builtin_amdgcn_global_load_lds(
            (gvoid*)(Vtb + base + (size_t)(gb + rl) * Sn + k0 + cg),
            (lvoid*)&Vts[buf][gb * 64], 16, 0, 0);
    };

    stage(0, 0);
    float4 md[4];
    #pragma unroll
    for (int ct = 0; ct < 4; ++ct)
        md[ct] = *(const float4*)(modrow + ct * 16 + quad * 4);
    __syncthreads();

    constexpr int NT = Sn / 64;
    for (int t = 0; t < NT; ++t) {
        const int cur = t & 1;

        float4 mdn[4];
        if (t + 1 < NT) {
            stage(t + 1, cur ^ 1);
            #pragma unroll
            for (int ct = 0; ct < 4; ++ct)
                mdn[ct] = *(const float4*)(modrow + (t + 1) * 64 + ct * 16 + quad * 4);
        }

        float e[4][4];
        #pragma unroll
        for (int ct = 0; ct < 4; ++ct) {
            f32x4 s = {};
            #pragma unroll
            for (int ks = 0; ks < 64; ks += 32) {
                bf16x8 kf = *(const bf16x8*)&Ks[cur][sidx(ct * 16 + l15, ks + quad * 8)];
                s = __builtin_amdgcn_mfma_f32_16x16x32_bf16(kf, ks ? qf1 : qf0, s, 0, 0, 0);
            }
            #pragma unroll
            for (int i = 0; i < 4; ++i)
                e[ct][i] = fmaf(s[i], (&md[ct].x)[i], qbias);
        }

        float pm[4];
        #pragma unroll
        for (int ct = 0; ct < 4; ++ct)
            pm[ct] = fmaxf(fmaxf(e[ct][0], e[ct][1]), fmaxf(e[ct][2], e[ct][3]));
        float pmax = fmaxf(fmaxf(pm[0], pm[1]), fmaxf(pm[2], pm[3]));
        pmax = fmaxf(pmax, __shfl_xor(pmax, 16));
        pmax = fmaxf(pmax, __shfl_xor(pmax, 32));

        if (__any(pmax > m_r + 8.0f)) {
            const float mnew  = fmaxf(m_r, pmax);
            const float alpha = __builtin_amdgcn_exp2f(m_r - mnew);
            m_r = mnew;
            l_r *= alpha;
            float aO[4];
            #pragma unroll
            for (int i = 0; i < 4; ++i)
                aO[i] = __shfl(alpha, quad * 4 + i, 16);
            #pragma unroll
            for (int ct = 0; ct < 4; ++ct)
                #pragma unroll
                for (int i = 0; i < 4; ++i)
                    O[ct][i] *= aO[i];
        }

        float rsc[4];
        #pragma unroll
        for (int ct = 0; ct < 4; ++ct) {
            bf16x4 pb;
            float pf[4];
            #pragma unroll
            for (int i = 0; i < 4; ++i) {
                const bf16 p = (bf16)__builtin_amdgcn_exp2f(e[ct][i] - m_r);
                pb[i] = p;
                pf[i] = (float)p;
            }
            rsc[ct] = (pf[0] + pf[1]) + (pf[2] + pf[3]);
            *(bf16x4*)&Ps[sidx(w * 16 + l15, ct * 16 + quad * 4)] = pb;
        }
        float rs = (rsc[0] + rsc[1]) + (rsc[2] + rsc[3]);
        rs += __shfl_xor(rs, 16);
        rs += __shfl_xor(rs, 32);
        l_r += rs;

        #pragma unroll
        for (int ks = 0; ks < 64; ks += 32) {
            bf16x8 paf = *(const bf16x8*)&Ps[sidx(w * 16 + l15, ks + quad * 8)];
            #pragma unroll
            for (int ct = 0; ct < 4; ++ct) {
                bf16x8 vf = *(const bf16x8*)&Vts[cur][sidx(ct * 16 + l15, ks + quad * 8)];
                O[ct] = __builtin_amdgcn_mfma_f32_16x16x32_bf16(paf, vf, O[ct], 0, 0, 0);
            }
        }

        if (t + 1 < NT) {
            #pragma unroll
            for (int ct = 0; ct < 4; ++ct)
                md[ct] = mdn[ct];
        }
        __syncthreads();
    }

    float lO[4];
    #pragma unroll
    for (int i = 0; i < 4; ++i)
        lO[i] = 1.0f / __shfl(l_r, quad * 4 + i, 16);
    #pragma unroll
    for (int ct = 0; ct < 4; ++ct)
        #pragma unroll
        for (int i = 0; i < 4; ++i) {
            const int row = q0 + w * 16 + quad * 4 + i;
            const int col = h * HDn + ct * 16 + l15;
            att[((size_t)b * Sn + row) * Dn + col] = (bf16)(O[ct][i] * lO[i]);
        }
}

// ---------------------------------------------------------------------------
// Launch
// ---------------------------------------------------------------------------
extern "C" void kernel_launch(void* const* d_in, const int* in_sizes, int n_in,
                              void* d_out, int out_size, void* d_ws, size_t ws_size,
                              hipStream_t stream) {
    const float* x   = (const float*)d_in[0];
    const int*   kpm = (const int*)d_in[1];
    const float* mod = (const float*)d_in[2];
    const float* Wq  = (const float*)d_in[3];
    const float* bq  = (const float*)d_in[4];
    const float* Wk  = (const float*)d_in[5];
    const float* bk  = (const float*)d_in[6];
    const float* Wv  = (const float*)d_in[7];
    const float* bv  = (const float*)d_in[8];
    const float* Wo  = (const float*)d_in[9];
    const float* bo  = (const float*)d_in[10];
    float* out = (float*)d_out;

    // Workspace (bf16 unless noted): xb,qb,kb,vtb,attb (8.4M each) +
    // wqt|wkt|wvt|wot (1M each, contiguous -> wqt is Wqkv^T [3072][1024]) +
    // bqkv (3072 f32)
    bf16* ws = (bf16*)d_ws;
    const size_t sz = (size_t)Bn * Sn * Dn;   // 8388608
    const size_t wz = (size_t)Dn * Dn;        // 1048576
    bf16* xb   = ws;
    bf16* qb   = ws + sz;
    bf16* kb   = ws + 2 * sz;
    bf16* vtb  = ws + 3 * sz;
    bf16* attb = ws + 4 * sz;
    bf16* wqt  = ws + 5 * sz;
    bf16* wkt  = wqt + wz;
    bf16* wvt  = wkt + wz;
    bf16* wot  = wvt + wz;
    float* bqkv = (float*)(wot + wz);

    conv_f32_bf16_k<<<(int)(sz / 1024), 256, 0, stream>>>(x, xb, (int)sz);
    conv_wt_k<<<dim3(16, 16, 4), 256, 0, stream>>>(Wq, Wk, Wv, Wo, wqt, wkt, wvt, wot);
    bias_cat_k<<<12, 256, 0, stream>>>(bq, bk, bv, bqkv);

    // 0.125 (1/sqrt(hd)) * log2(e): folded into Q so attn runs in log2 domain
    const float SC = 0.125f * 1.44269504088896340736f;

    // Fused QKV: M=8192, N=3072, K=1024 -> 384 blocks of 256^2
    gemm_qkv_k<<<384, 512, 0, stream>>>(xb, wqt, bqkv, qb, kb, vtb, SC);

    attn_mfma_k<<<Bn * Hn * (Sn / 128), 512, 0, stream>>>(qb, kb, vtb, kpm, mod, attb);

    gemm_out_k<<<128, 512, 0, stream>>>(attb, wot, bo, out);
}

// Round 11
// 430.416 us; speedup vs baseline: 1.0905x; 1.0905x over previous
//
#include <hip/hip_runtime.h>
#include <cstddef>
#include <cstdint>

// Problem constants: B=4, S=2048, D=1024, H=16, HD=64
constexpr int Bn  = 4;
constexpr int Sn  = 2048;
constexpr int Dn  = 1024;
constexpr int Hn  = 16;
constexpr int HDn = 64;

typedef __bf16 bf16;
typedef __attribute__((ext_vector_type(8))) __bf16 bf16x8;
typedef __attribute__((ext_vector_type(4))) __bf16 bf16x4;
typedef __attribute__((ext_vector_type(4))) float  f32x4;

typedef __attribute__((address_space(1))) const void gvoid;
typedef __attribute__((address_space(3))) void lvoid;

// ---------------------------------------------------------------------------
// Elementwise fp32 -> bf16 (x staging)
// ---------------------------------------------------------------------------
__global__ __launch_bounds__(256) void conv_f32_bf16_k(
    const float* __restrict__ in, bf16* __restrict__ out, int n)
{
    int i = (blockIdx.x * 256 + threadIdx.x) * 4;
    if (i + 3 < n) {
        float4 v = *(const float4*)(in + i);
        bf16 o[4] = {(bf16)v.x, (bf16)v.y, (bf16)v.z, (bf16)v.w};
        *(ulong1*)(out + i) = *(ulong1*)o;  // 8B store
    }
}

// ---------------------------------------------------------------------------
// Bias concat: [bq|bk|bv] -> float[3072]
// ---------------------------------------------------------------------------
__global__ __launch_bounds__(256) void bias_cat_k(
    const float* __restrict__ bq, const float* __restrict__ bk,
    const float* __restrict__ bv, float* __restrict__ o)
{
    const int i = blockIdx.x * 256 + threadIdx.x;   // grid 12 -> 3072
    if (i < 1024)      o[i] = bq[i];
    else if (i < 2048) o[i] = bk[i - 1024];
    else if (i < 3072) o[i] = bv[i - 2048];
}

// ---------------------------------------------------------------------------
// Weight transpose + convert: W[k][n] fp32 -> Wt[n][k] bf16. 64x64 tiles.
// ---------------------------------------------------------------------------
__global__ __launch_bounds__(256) void conv_wt_k(
    const float* __restrict__ w0, const float* __restrict__ w1,
    const float* __restrict__ w2, const float* __restrict__ w3,
    bf16* __restrict__ o0, bf16* __restrict__ o1,
    bf16* __restrict__ o2, bf16* __restrict__ o3)
{
    const float* W = (blockIdx.z == 0) ? w0 : (blockIdx.z == 1) ? w1
                   : (blockIdx.z == 2) ? w2 : w3;
    bf16* O = (blockIdx.z == 0) ? o0 : (blockIdx.z == 1) ? o1
            : (blockIdx.z == 2) ? o2 : o3;
    __shared__ float t[64][65];
    const int tid = threadIdx.x;
    const int k0 = blockIdx.x * 64;   // row of W (k-dim)
    const int n0 = blockIdx.y * 64;   // col of W (n-dim)
    #pragma unroll
    for (int p = 0; p < 16; ++p) {
        const int idx = p * 256 + tid;
        const int r = idx >> 6, c = idx & 63;
        t[r][c] = W[(size_t)(k0 + r) * Dn + n0 + c];
    }
    __syncthreads();
    #pragma unroll
    for (int p = 0; p < 16; ++p) {
        const int idx = p * 256 + tid;
        const int r = idx >> 6, c = idx & 63;   // r: n-offset, c: k-offset
        O[(size_t)(n0 + r) * Dn + k0 + c] = (bf16)t[c][r];
    }
}

// ---------------------------------------------------------------------------
// GEMM: REVERTED to the twice-passing R8/R9 best (128^2 tile, counted vmcnt).
// R10's 256^2 single-buffer regressed (matches m105/m112: 256^2 only pays in
// deep-pipelined schedules). ~190-196 us for QKV+out at this config.
// ---------------------------------------------------------------------------
#define GEMM_STAGE(Ap, Bp, k0, boff)                                          \
    {                                                                         \
        _Pragma("unroll")                                                     \
        for (int j = 0; j < 4; ++j) {                                         \
            const int rbase = (w * 4 + j) * 8;                                \
            const int r = rbase + srow;                                       \
            __builtin_amdgcn_global_load_lds(                                 \
                (gvoid*)(Ap + (size_t)(m0 + r) * Dn + (k0) + scol),           \
                (lvoid*)&smem[(boff) + rbase * 64], 16, 0, 0);                \
            __builtin_amdgcn_global_load_lds(                                 \
                (gvoid*)(Bp + (size_t)(n0 + r) * Dn + (k0) + scol),           \
                (lvoid*)&smem[(boff) + 128 * 64 + rbase * 64], 16, 0, 0);     \
        }                                                                     \
    }

#define GEMM_COMPUTE(boff)                                                    \
    {                                                                         \
        _Pragma("unroll")                                                     \
        for (int ks = 0; ks < 64; ks += 32) {                                 \
            bf16x8 af[4], bfr[4];                                             \
            _Pragma("unroll")                                                 \
            for (int fm = 0; fm < 4; ++fm)                                    \
                af[fm] = *(const bf16x8*)&smem[(boff) +                       \
                    (wm * 64 + fm * 16 + l15) * 64 + ks + quad * 8];          \
            _Pragma("unroll")                                                 \
            for (int fn = 0; fn < 4; ++fn)                                    \
                bfr[fn] = *(const bf16x8*)&smem[(boff) + 128 * 64 +           \
                    (wn * 64 + fn * 16 + l15) * 64 + ks + quad * 8];          \
            _Pragma("unroll")                                                 \
            for (int fm = 0; fm < 4; ++fm)                                    \
                _Pragma("unroll")                                             \
                for (int fn = 0; fn < 4; ++fn)                                \
                    acc[fm][fn] = __builtin_amdgcn_mfma_f32_16x16x32_bf16(    \
                        af[fm], bfr[fn], acc[fm][fn], 0, 0, 0);               \
        }                                                                     \
    }

#define GEMM_KLOOP(Ap, Bp)                                                    \
    GEMM_STAGE(Ap, Bp, 0, 0);                                                 \
    int boff = 0;                                                             \
    for (int kt = 0; kt < Dn / 64; ++kt) {                                    \
        if (kt + 1 < Dn / 64) {                                               \
            GEMM_STAGE(Ap, Bp, (kt + 1) * 64, boff ^ BUF);                    \
            asm volatile("s_waitcnt vmcnt(8)" ::: "memory");                  \
        } else {                                                              \
            asm volatile("s_waitcnt vmcnt(0)" ::: "memory");                  \
        }                                                                     \
        __builtin_amdgcn_s_barrier();                                         \
        __builtin_amdgcn_sched_barrier(0);                                    \
        GEMM_COMPUTE(boff);                                                   \
        __builtin_amdgcn_sched_barrier(0);                                    \
        __builtin_amdgcn_s_barrier();                                         \
        boff ^= BUF;                                                          \
    }

constexpr int BUF = 2 * 128 * 64;   // elements per (A,B) buffer pair

// ---------------------------------------------------------------------------
// Final-projection GEMM: out_f32 = A(8192x1024) @ Bt^T + bias.
// ---------------------------------------------------------------------------
__global__ __launch_bounds__(256) void gemm_out_k(
    const bf16* __restrict__ A, const bf16* __restrict__ Bt,
    const float* __restrict__ bias, float* __restrict__ outv)
{
    __shared__ __align__(16) bf16 smem[2 * BUF];

    const int tid  = threadIdx.x;
    const int w    = tid >> 6;
    const int lane = tid & 63;
    const int quad = lane >> 4;
    const int l15  = lane & 15;
    const int m0   = blockIdx.x * 128;
    const int n0   = blockIdx.y * 128;
    const int wm   = w >> 1;
    const int wn   = w & 1;
    const int srow = lane >> 3;
    const int scol = (lane & 7) * 8;

    f32x4 acc[4][4] = {};

    GEMM_KLOOP(A, Bt);

    #pragma unroll
    for (int fn = 0; fn < 4; ++fn) {
        const int c = n0 + wn * 64 + fn * 16 + l15;
        const float bv = bias[c];
        #pragma unroll
        for (int fm = 0; fm < 4; ++fm)
            #pragma unroll
            for (int i = 0; i < 4; ++i) {
                const int m = m0 + wm * 64 + fm * 16 + quad * 4 + i;
                outv[(size_t)m * Dn + c] = acc[fm][fn][i] + bv;
            }
    }
}

// ---------------------------------------------------------------------------
// FUSED QKV GEMM: A(8192x1024) @ Wqkv^T(3072x1024) + bias_cat, grid 64x24.
// ---------------------------------------------------------------------------
__global__ __launch_bounds__(256) void gemm_qkv_k(
    const bf16* __restrict__ A, const bf16* __restrict__ Wt,
    const float* __restrict__ bias, bf16* __restrict__ qout,
    bf16* __restrict__ kout, bf16* __restrict__ vout, float scq)
{
    __shared__ __align__(16) bf16 smem[2 * BUF];   // 64KB; V-transpose reuses

    const int tid  = threadIdx.x;
    const int w    = tid >> 6;
    const int lane = tid & 63;
    const int quad = lane >> 4;
    const int l15  = lane & 15;
    const int m0   = blockIdx.x * 128;
    const int n0   = blockIdx.y * 128;   // in [0, 3072)
    const int wm   = w >> 1;
    const int wn   = w & 1;
    const int srow = lane >> 3;
    const int scol = (lane & 7) * 8;

    f32x4 acc[4][4] = {};

    GEMM_KLOOP(A, Wt);

    const int sec = n0 >> 10;            // 0=Q, 1=K, 2=V (block-uniform)
    const int cb  = n0 & 1023;           // column base within the section

    if (sec < 2) {
        bf16* const outp = sec ? kout : qout;
        const float scale = sec ? 1.0f : scq;
        #pragma unroll
        for (int fn = 0; fn < 4; ++fn) {
            const int cc = cb + wn * 64 + fn * 16 + l15;
            const float bv = bias[n0 + wn * 64 + fn * 16 + l15];
            const int h = cc >> 6, hd = cc & 63;
            #pragma unroll
            for (int fm = 0; fm < 4; ++fm)
                #pragma unroll
                for (int i = 0; i < 4; ++i) {
                    const int m = m0 + wm * 64 + fm * 16 + quad * 4 + i;
                    const int b = m >> 11, s = m & (Sn - 1);
                    outp[(((size_t)(b * Hn + h) * Sn) + s) * HDn + hd] =
                        (bf16)((acc[fm][fn][i] + bv) * scale);
                }
        }
    } else {
        // V: transpose through LDS (pad 136), then coalesced 256B row stores.
        bf16* const T = smem;    // reuse after final barrier of the main loop
        #pragma unroll
        for (int fn = 0; fn < 4; ++fn) {
            const int n = wn * 64 + fn * 16 + l15;
            const float bv = bias[n0 + n];
            #pragma unroll
            for (int fm = 0; fm < 4; ++fm) {
                const int m = wm * 64 + fm * 16 + quad * 4;
                bf16x4 pk;
                #pragma unroll
                for (int i = 0; i < 4; ++i)
                    pk[i] = (bf16)(acc[fm][fn][i] + bv);
                *(bf16x4*)&T[n * 136 + m] = pk;
            }
        }
        __syncthreads();
        const int b  = m0 >> 11;
        const int s0 = m0 & (Sn - 1);
        #pragma unroll
        for (int it = 0; it < 8; ++it) {
            const int n    = it * 16 + (tid >> 4);       // 0..127
            const int mcol = (tid & 15) * 8;
            const int gh = (cb + n) >> 6, ghd = (cb + n) & 63;
            bf16x8 v = *(const bf16x8*)&T[n * 136 + mcol];
            *(bf16x8*)(vout +
                (((size_t)(b * Hn + gh) * HDn) + ghd) * Sn + s0 + mcol) = v;
        }
    }
}

// ---------------------------------------------------------------------------
// LDS XOR-swizzle (element-index form): 16B chunk column ^= row&7.
// ---------------------------------------------------------------------------
__device__ __forceinline__ int sidx(int r, int c) {
    return r * 64 + (c ^ ((r & 7) << 3));
}

__device__ __forceinline__ uint32_t pack2(bf16 a, bf16 b) {
    union { bf16 h[2]; uint32_t u; } x;
    x.h[0] = a; x.h[1] = b;          // h[0] = low 16 bits = even (lower-k) elem
    return x.u;
}

// ---------------------------------------------------------------------------
// Flash attention: QBLK=128 @ 512 thr; this revision removes the Ps LDS
// round-trip entirely (T12-analog for 16x16 fragments):
//   lane (g=quad, l=l15) holds P[q=l][k=16c+4g+i] after swapped QK^T.
//   PV A-frag needs P[q=l][k=ks+8g+j] = union of partner quads
//   pA=((g&1)<<5)+l, pB=pA+16, word class c=(g>>1)+2*half.
//   16 shfl (ds_bpermute) + 8 selects replace 4 ds_write + 2 ds_read + RAW.
//   Layout hand-verified on 4 (lane, half) instances.
// => Ps deleted: LDS 48->32 KB -> 4 blocks/CU (32 waves = HW cap), and the
//    4.2M Ps bank-conflict cycles go away. T5 setprio wraps MFMA clusters
//    (attn +4-7% measured, m191 — independent-block regime applies here).
// ---------------------------------------------------------------------------
__global__ __launch_bounds__(512, 6) void attn_mfma_k(
    const bf16* __restrict__ Qb, const bf16* __restrict__ Kb,
    const bf16* __restrict__ Vtb, const int* __restrict__ kpm,
    const float* __restrict__ mod, bf16* __restrict__ att)
{
    __shared__ __align__(16) bf16 Ks[2][64 * 64];
    __shared__ __align__(16) bf16 Vts[2][64 * 64];

    const int tid  = threadIdx.x;
    const int w    = tid >> 6;             // 0..7
    const int lane = tid & 63;
    const int quad = lane >> 4;
    const int l15  = lane & 15;
    const int blk  = blockIdx.x;
    const int bh   = blk >> 4;             // q-tile innermost: K/V L2-reuse
    const int q0   = (blk & 15) * 128;
    const int b    = bh >> 4;
    const int h    = bh & 15;
    const size_t base = (size_t)bh * Sn * HDn;

    const int qrow = q0 + w * 16 + l15;    // this lane's softmax q-row
    const bf16x8 qf0 = *(const bf16x8*)(Qb + base + (size_t)qrow * HDn + 0  + quad * 8);
    const bf16x8 qf1 = *(const bf16x8*)(Qb + base + (size_t)qrow * HDn + 32 + quad * 8);

    const float qbias = (kpm[(size_t)b * Sn + qrow] != 0) ? -1e30f : 0.0f;
    const float* modrow = mod + ((size_t)b * Sn + qrow) * Sn;

    float m_r = -1e30f;
    float l_r = 0.0f;
    f32x4 O[4] = {};

    const int rl = lane >> 3;                       // 0..7
    const int cg = ((lane & 7) ^ rl) * 8;           // swizzled source elems
    const int gb = w * 8;                           // group base row

    auto stage = [&](int t, int buf) {
        const int k0 = t * 64;
        __builtin_amdgcn_global_load_lds(
            (gvoid*)(Kb + base + (size_t)(k0 + gb + rl) * HDn + cg),
            (lvoid*)&Ks[buf][gb * 64], 16, 0, 0);
        __builtin_amdgcn_global_load_lds(
            (gvoid*)(Vtb + base + (size_t)(gb + rl) * Sn + k0 + cg),
            (lvoid*)&Vts[buf][gb * 64], 16, 0, 0);
    };

    stage(0, 0);
    float4 md[4];
    #pragma unroll
    for (int ct = 0; ct < 4; ++ct)
        md[ct] = *(const float4*)(modrow + ct * 16 + quad * 4);
    __syncthreads();

    // Partner lanes for the in-register P redistribution
    const int pA = ((quad & 1) << 5) + l15;
    const int pB = pA + 16;

    constexpr int NT = Sn / 64;
    for (int t = 0; t < NT; ++t) {
        const int cur = t & 1;

        float4 mdn[4];
        if (t + 1 < NT) {
            stage(t + 1, cur ^ 1);
            #pragma unroll
            for (int ct = 0; ct < 4; ++ct)
                mdn[ct] = *(const float4*)(modrow + (t + 1) * 64 + ct * 16 + quad * 4);
        }

        // QK^T (swapped): lane holds e[k = ct*16+quad*4+i] for its q-row
        float e[4][4];
        __builtin_amdgcn_s_setprio(1);
        #pragma unroll
        for (int ct = 0; ct < 4; ++ct) {
            f32x4 s = {};
            #pragma unroll
            for (int ks = 0; ks < 64; ks += 32) {
                bf16x8 kf = *(const bf16x8*)&Ks[cur][sidx(ct * 16 + l15, ks + quad * 8)];
                s = __builtin_amdgcn_mfma_f32_16x16x32_bf16(kf, ks ? qf1 : qf0, s, 0, 0, 0);
            }
            #pragma unroll
            for (int i = 0; i < 4; ++i)
                e[ct][i] = fmaf(s[i], (&md[ct].x)[i], qbias);
        }
        __builtin_amdgcn_s_setprio(0);

        // row max: tree + 2 cross-quad shfl
        float pm[4];
        #pragma unroll
        for (int ct = 0; ct < 4; ++ct)
            pm[ct] = fmaxf(fmaxf(e[ct][0], e[ct][1]), fmaxf(e[ct][2], e[ct][3]));
        float pmax = fmaxf(fmaxf(pm[0], pm[1]), fmaxf(pm[2], pm[3]));
        pmax = fmaxf(pmax, __shfl_xor(pmax, 16));
        pmax = fmaxf(pmax, __shfl_xor(pmax, 32));

        // T13 defer-max
        if (__any(pmax > m_r + 8.0f)) {
            const float mnew  = fmaxf(m_r, pmax);
            const float alpha = __builtin_amdgcn_exp2f(m_r - mnew);
            m_r = mnew;
            l_r *= alpha;
            float aO[4];
            #pragma unroll
            for (int i = 0; i < 4; ++i)
                aO[i] = __shfl(alpha, quad * 4 + i, 16);
            #pragma unroll
            for (int ct = 0; ct < 4; ++ct)
                #pragma unroll
                for (int i = 0; i < 4; ++i)
                    O[ct][i] *= aO[i];
        }

        // P = exp2(e - m) in bf16, packed into 8 u32 words pk[c][b] =
        // pair(P[k=16c+4g+2b], P[k=16c+4g+2b+1]); rs sums rounded values.
        float rsc[4];
        uint32_t pk[4][2];                 // constant-indexed after unroll
        #pragma unroll
        for (int ct = 0; ct < 4; ++ct) {
            bf16 pb[4]; float pf[4];
            #pragma unroll
            for (int i = 0; i < 4; ++i) {
                pb[i] = (bf16)__builtin_amdgcn_exp2f(e[ct][i] - m_r);
                pf[i] = (float)pb[i];
            }
            rsc[ct] = (pf[0] + pf[1]) + (pf[2] + pf[3]);
            pk[ct][0] = pack2(pb[0], pb[1]);
            pk[ct][1] = pack2(pb[2], pb[3]);
        }
        float rs = (rsc[0] + rsc[1]) + (rsc[2] + rsc[3]);
        rs += __shfl_xor(rs, 16);
        rs += __shfl_xor(rs, 32);
        l_r += rs;

        // O += P V with P gathered in-register (no LDS round-trip).
        __builtin_amdgcn_s_setprio(1);
        #pragma unroll
        for (int half = 0; half < 2; ++half) {
            const int cL = half * 2;       // word class for dst quads 0,1
            const int cH = half * 2 + 1;   // word class for dst quads 2,3
            uint32_t X0 = __shfl(pk[cL][0], pA, 64);
            uint32_t X1 = __shfl(pk[cL][1], pA, 64);
            uint32_t X2 = __shfl(pk[cL][0], pB, 64);
            uint32_t X3 = __shfl(pk[cL][1], pB, 64);
            uint32_t Y0 = __shfl(pk[cH][0], pA, 64);
            uint32_t Y1 = __shfl(pk[cH][1], pA, 64);
            uint32_t Y2 = __shfl(pk[cH][0], pB, 64);
            uint32_t Y3 = __shfl(pk[cH][1], pB, 64);
            union { uint32_t u[4]; bf16x8 v; } fr;
            fr.u[0] = (quad & 2) ? Y0 : X0;
            fr.u[1] = (quad & 2) ? Y1 : X1;
            fr.u[2] = (quad & 2) ? Y2 : X2;
            fr.u[3] = (quad & 2) ? Y3 : X3;
            const bf16x8 paf = fr.v;
            #pragma unroll
            for (int ct = 0; ct < 4; ++ct) {
                bf16x8 vf = *(const bf16x8*)&Vts[cur][sidx(ct * 16 + l15, half * 32 + quad * 8)];
                O[ct] = __builtin_amdgcn_mfma_f32_16x16x32_bf16(paf, vf, O[ct], 0, 0, 0);
            }
        }
        __builtin_amdgcn_s_setprio(0);

        if (t + 1 < NT) {
            #pragma unroll
            for (int ct = 0; ct < 4; ++ct)
                md[ct] = mdn[ct];
        }
        __syncthreads();
    }

    float lO[4];
    #pragma unroll
    for (int i = 0; i < 4; ++i)
        lO[i] = 1.0f / __shfl(l_r, quad * 4 + i, 16);
    #pragma unroll
    for (int ct = 0; ct < 4; ++ct)
        #pragma unroll
        for (int i = 0; i < 4; ++i) {
            const int row = q0 + w * 16 + quad * 4 + i;
            const int col = h * HDn + ct * 16 + l15;
            att[((size_t)b * Sn + row) * Dn + col] = (bf16)(O[ct][i] * lO[i]);
        }
}

// ---------------------------------------------------------------------------
// Launch
// ---------------------------------------------------------------------------
extern "C" void kernel_launch(void* const* d_in, const int* in_sizes, int n_in,
                              void* d_out, int out_size, void* d_ws, size_t ws_size,
                              hipStream_t stream) {
    const float* x   = (const float*)d_in[0];
    const int*   kpm = (const int*)d_in[1];
    const float* mod = (const float*)d_in[2];
    const float* Wq  = (const float*)d_in[3];
    const float* bq  = (const float*)d_in[4];
    const float* Wk  = (const float*)d_in[5];
    const float* bk  = (const float*)d_in[6];
    const float* Wv  = (const float*)d_in[7];
    const float* bv  = (const float*)d_in[8];
    const float* Wo  = (const float*)d_in[9];
    const float* bo  = (const float*)d_in[10];
    float* out = (float*)d_out;

    // Workspace (bf16 unless noted): xb,qb,kb,vtb,attb (8.4M each) +
    // wqt|wkt|wvt|wot (1M each, contiguous -> wqt is Wqkv^T [3072][1024]) +
    // bqkv (3072 f32)
    bf16* ws = (bf16*)d_ws;
    const size_t sz = (size_t)Bn * Sn * Dn;   // 8388608
    const size_t wz = (size_t)Dn * Dn;        // 1048576
    bf16* xb   = ws;
    bf16* qb   = ws + sz;
    bf16* kb   = ws + 2 * sz;
    bf16* vtb  = ws + 3 * sz;
    bf16* attb = ws + 4 * sz;
    bf16* wqt  = ws + 5 * sz;
    bf16* wkt  = wqt + wz;
    bf16* wvt  = wkt + wz;
    bf16* wot  = wvt + wz;
    float* bqkv = (float*)(wot + wz);

    conv_f32_bf16_k<<<(int)(sz / 1024), 256, 0, stream>>>(x, xb, (int)sz);
    conv_wt_k<<<dim3(16, 16, 4), 256, 0, stream>>>(Wq, Wk, Wv, Wo, wqt, wkt, wvt, wot);
    bias_cat_k<<<12, 256, 0, stream>>>(bq, bk, bv, bqkv);

    // 0.125 (1/sqrt(hd)) * log2(e): folded into Q so attn runs in log2 domain
    const float SC = 0.125f * 1.44269504088896340736f;

    // Fused QKV: M=8192, N=3072, K=1024 -> grid 64x24
    gemm_qkv_k<<<dim3(64, 24), 256, 0, stream>>>(xb, wqt, bqkv, qb, kb, vtb, SC);

    attn_mfma_k<<<Bn * Hn * (Sn / 128), 512, 0, stream>>>(qb, kb, vtb, kpm, mod, attb);

    gemm_out_k<<<dim3(64, 8), 256, 0, stream>>>(attb, wot, bo, out);
}